// Round 12
// baseline (2083.849 us; speedup 1.0000x reference)
//
#include <hip/hip_runtime.h>
#include <hip/hip_bf16.h>

typedef unsigned short u16;
typedef unsigned int u32;
typedef __attribute__((ext_vector_type(8))) short short8;
typedef __attribute__((ext_vector_type(4))) float f32x4;

// sizes: V=50000 E=256 H=512 T=50 C=5 B=128 S=512 FC1=500, 4H=2048
// ALL float tensors are f32 on device; x is int32; d_out is f32.
// PROTOCOL LAWS: one tier (sc0 sc1); vmcnt(0) only (fused in-asm); watchdog.
// h transported as self-validating 16B units {6 bf16 + u32 step-tag}.
// NEW (R12): per-WAVE shfl-pack publish right after gates — no ldsP, no 3rd barrier.

__device__ __forceinline__ float bf2f(u16 v){ union{u32 u; float f;} x; x.u = ((u32)v)<<16; return x.f; }
__device__ __forceinline__ u16 f2bf(float f){ union{float f; u32 u;} x; x.f = f; u32 r = ((x.u>>16)&1u) + 0x7FFFu; return (u16)((x.u + r)>>16); }
__device__ __forceinline__ float sigf(float x){ return 1.f/(1.f+__expf(-x)); }
__device__ __forceinline__ float tanh_f(float x){ return 2.f/(1.f+__expf(-2.f*x)) - 1.f; }

#define POLL_GUARD (1u<<14)

// unit index (within parity): (((g*2+plane)*8+row)*16+prod)*6+u ; 24576/parity.

// ---- transpose+cast: W_h f32 [512][2048] -> WhT bf16 [2048][512]
//                      W_x f32 [256][2048] -> WxT bf16 [2048][256]
__global__ void k_prep(const float* __restrict__ Wh, const float* __restrict__ Wx,
                       u16* __restrict__ WhT, u16* __restrict__ WxT){
  __shared__ u16 tile[32][33];
  int b = blockIdx.x;
  const float* src; u16* dst; int K, kt, nt;
  if (b < 1024){ src = Wh; dst = WhT; K = 512; kt = b & 15; nt = b >> 4; }
  else { b -= 1024; src = Wx; dst = WxT; K = 256; kt = b & 7; nt = b >> 3; }
  int tx = threadIdx.x, ty = threadIdx.y;
  #pragma unroll
  for (int p = 0; p < 4; ++p){
    int r = p*8 + ty;
    tile[r][tx] = f2bf(src[(kt*32 + r)*2048 + nt*32 + tx]);
  }
  __syncthreads();
  #pragma unroll
  for (int p = 0; p < 4; ++p){
    int r = p*8 + ty;
    dst[(nt*32 + r)*K + kt*32 + tx] = tile[tx][r];
  }
}

// ---- tb[b][col] = bias[col] + sum_t topic[b][t]*W_t[t][col]   (all f32)
__global__ void k_topic(const float* __restrict__ topic, const float* __restrict__ Wt,
                        const float* __restrict__ bias, float* __restrict__ tb){
  int b = blockIdx.y;
  int col = blockIdx.x*256 + threadIdx.x;
  float acc = bias[col];
  #pragma unroll 5
  for (int t = 0; t < 50; ++t)
    acc += topic[b*50 + t] * Wt[t*2048 + col];
  tb[b*2048 + col] = acc;
}

// ---- init units: parity0 = h0 split hi/lo, tag 0; parity1 = tag 0xFFFFFFFF.
__global__ void k_init(const float* __restrict__ h0, u32* __restrict__ U){
  int uid = blockIdx.x*256 + threadIdx.x;
  int parity = (uid >= 24576) ? 1 : 0;
  int rem = uid - parity*24576;
  int g     = rem / 1536;   int r2 = rem - g*1536;
  int plane = r2 / 768;     int pid = r2 - plane*768;
  int row   = pid / 96;     int p3 = pid - row*96;
  int prod  = p3 / 6;       int u  = p3 - prod*6;
  u32 d0=0, d1=0, d2=0, d3;
  if (parity == 0){
    const float* hr = h0 + (g*8 + row)*512 + prod*32 + u*6;
    int nv = 32 - u*6; if (nv > 6) nv = 6;
    u16 vals[6] = {0,0,0,0,0,0};
    for (int j = 0; j < nv; ++j){
      float v = hr[j];
      u16 hi = f2bf(v);
      vals[j] = plane ? f2bf(v - bf2f(hi)) : hi;
    }
    d0 = (u32)vals[0] | ((u32)vals[1]<<16);
    d1 = (u32)vals[2] | ((u32)vals[3]<<16);
    d2 = (u32)vals[4] | ((u32)vals[5]<<16);
    d3 = 0u;                  // tag = 0 (state S_0)
  } else {
    d3 = 0xFFFFFFFFu;         // invalid tag
  }
  u32* dst = U + (size_t)uid*4;
  dst[0]=d0; dst[1]=d1; dst[2]=d2; dst[3]=d3;
}

// ---- persistent LSTM: 256 wgs = 16 batch-groups (8 rows) x 16 col-wgs
__global__ void __launch_bounds__(256, 1)
k_rnn(const int* __restrict__ x, const float* __restrict__ embed, const float* __restrict__ c0,
      const u16* __restrict__ WhT, const u16* __restrict__ WxT, const float* __restrict__ tb,
      u32* __restrict__ U, float* __restrict__ hf)
{
  const int bx = blockIdx.x;
  const int g = bx & 15;      // batch group
  const int w = bx >> 4;      // h-column chunk [w*32, w*32+32)
  const int tid = threadIdx.x;
  const int v = tid >> 6;     // wave 0..3
  const int lane = tid & 63;
  const int l15 = lane & 15, l4 = lane >> 4;
  const int arr = l15 & 7;    // A row within 8
  const int pl  = l15 >> 3;   // 0 = hi plane, 1 = lo plane

  // ldsH: 40 u16 per producer slot (pad) + row*8 stagger (write & read both shifted).
  __shared__ __align__(16) u16 ldsH[2][8][704];   // 22KB
  __shared__ __align__(16) float ldsD[16][132];   // 8.4KB
  __shared__ int ldsX[8][512];                    // 16KB

  // epilogue cell: thread owns (row er, h-col ehc); wave v holds rows {2v,2v+1}:
  // er = tid>>5 = 2v + (lane>>5); cell col lane&31.
  const int er = tid >> 5, ehc = tid & 31;
  const int eb = g*8 + er;
  const int ecol = w*32 + ehc;
  float c_val = c0[eb*512 + ecol];
  const float tb0 = tb[eb*2048 +    0 + ecol];
  const float tb1 = tb[eb*2048 +  512 + ecol];
  const float tb2 = tb[eb*2048 + 1024 + ecol];
  const float tb3 = tb[eb*2048 + 1536 + ecol];

  // preload B fragments (step-invariant)
  short8 b2[2][16], b1[2][8];
  #pragma unroll
  for (int j = 0; j < 2; ++j){
    const int cl = (2*v + j)*16 + l15;
    const int cg = (cl & 3)*512 + w*32 + (cl >> 2);
    #pragma unroll
    for (int kt = 0; kt < 16; ++kt)
      b2[j][kt] = *(const short8*)(WhT + cg*512 + kt*32 + l4*8);
    #pragma unroll
    for (int kt = 0; kt < 8; ++kt)
      b1[j][kt] = *(const short8*)(WxT + cg*256 + kt*32 + l4*8);
  }

  // stage this group's x block into LDS (8 rows x 512)
  {
    const int4* src = (const int4*)(x + g*4096);
    int4* dst = (int4*)&ldsX[0][0];
    #pragma unroll
    for (int i = 0; i < 4; ++i) dst[tid + 256*i] = src[tid + 256*i];
  }
  __syncthreads();

  // consumer decode: 3 unit slots per thread (pid = tid*3+i), hi plane; lo = +768
  int rw0,rw1,rw2, cb0,cb1,cb2; u32 of0,of1,of2;
  {
    int pid, row, p3, prod, u;
    pid = tid*3 + 0; row = pid/96; p3 = pid - row*96; prod = p3/6; u = p3 - prod*6;
    rw0 = row; cb0 = prod*40 + u*6 + row*8; of0 = (u32)((((g*2+0)*8+row)*16+prod)*6+u);
    pid = tid*3 + 1; row = pid/96; p3 = pid - row*96; prod = p3/6; u = p3 - prod*6;
    rw1 = row; cb1 = prod*40 + u*6 + row*8; of1 = (u32)((((g*2+0)*8+row)*16+prod)*6+u);
    pid = tid*3 + 2; row = pid/96; p3 = pid - row*96; prod = p3/6; u = p3 - prod*6;
    rw2 = row; cb2 = prod*40 + u*6 + row*8; of2 = (u32)((((g*2+0)*8+row)*16+prod)*6+u);
  }
  // per-wave publisher decode: lanes 0..23 of each wave publish 24 units
  // l<24: plane = l/12, rp = (l%12)/6, u = l%6, row = 2v+rp, src lanes rp*32+u*6+j
  int pub_plane = 0, pub_u = 0, pub_srcbase = 0; u32 pub_off = 0;
  {
    int l = lane < 24 ? lane : 0;
    pub_plane = l/12; int rem = l - pub_plane*12;
    int rp = rem/6; pub_u = rem - rp*6;
    pub_srcbase = rp*32 + pub_u*6;
    pub_off = (u32)((((g*2+pub_plane)*8 + (2*v+rp))*16 + w)*6 + pub_u);
  }
  // G-phase step-invariant read offsets
  int goff[16];
  #pragma unroll
  for (int kt = 0; kt < 16; ++kt) goff[kt] = kt*40 + l4*8 + arr*8;
  const u16* hrow = &ldsH[pl][arr][0];

  const short8 z8 = {0,0,0,0,0,0,0,0};
  short8 a1A[8], a1B[8];
  {
    const int idx0 = ldsX[arr][0];
    const float* ep = embed + (u32)idx0*256 + l4*8;
    #pragma unroll
    for (int kt = 0; kt < 8; ++kt){
      float4 f0 = *(const float4*)(ep + kt*32);
      float4 f1 = *(const float4*)(ep + kt*32 + 4);
      union { short8 s; u32 u[4]; } pk;
      asm("v_cvt_pk_bf16_f32 %0, %1, %2" : "=v"(pk.u[0]) : "v"(f0.x), "v"(f0.y));
      asm("v_cvt_pk_bf16_f32 %0, %1, %2" : "=v"(pk.u[1]) : "v"(f0.z), "v"(f0.w));
      asm("v_cvt_pk_bf16_f32 %0, %1, %2" : "=v"(pk.u[2]) : "v"(f1.x), "v"(f1.y));
      asm("v_cvt_pk_bf16_f32 %0, %1, %2" : "=v"(pk.u[3]) : "v"(f1.z), "v"(f1.w));
      a1A[kt] = (l15 < 8) ? pk.s : z8;   // rows 8..15: zero x-contribution
    }
  }

  union F4 { f32x4 f; u32 u[4]; };

  auto step = [&](int t, short8 (&a1c)[8], short8 (&a1n)[8]){
    // P0: issue next-step embedding loads (drained by the poll's in-asm vmcnt(0))
    const int tn = (t < 511) ? t + 1 : 511;
    const int idxn = ldsX[arr][tn];
    const float* ep = embed + (u32)idxn*256 + l4*8;
    f32x4 e[16];
    #pragma unroll
    for (int kt = 0; kt < 8; ++kt){
      asm volatile("global_load_dwordx4 %0, %2, off\n\t"
                   "global_load_dwordx4 %1, %3, off"
                   : "=v"(e[2*kt]), "=v"(e[2*kt+1])
                   : "v"(ep + kt*32), "v"(ep + kt*32 + 4));
    }
    // A: x-phase MFMAs (register-only)
    f32x4 aX0 = {0.f,0.f,0.f,0.f}, aX1 = {0.f,0.f,0.f,0.f};
    #pragma unroll
    for (int kt = 0; kt < 8; ++kt){
      aX0 = __builtin_amdgcn_mfma_f32_16x16x32_bf16(a1c[kt], b1[0][kt], aX0, 0, 0, 0);
      aX1 = __builtin_amdgcn_mfma_f32_16x16x32_bf16(a1c[kt], b1[1][kt], aX1, 0, 0, 0);
    }
    // B: tag-poll — 6 self-validating units per thread (tag==t => payload is S_t)
    F4 H0,H1,H2,L0,L1,L2;
    {
      const u32* b = U + (size_t)((t & 1)*24576)*4;
      const u32 *a0 = b + (size_t)of0*4,      *a1_ = b + (size_t)of1*4,      *a2 = b + (size_t)of2*4;
      const u32 *a3 = b + (size_t)(of0+768)*4,*a4 = b + (size_t)(of1+768)*4, *a5 = b + (size_t)(of2+768)*4;
      const u32 tg = (u32)t;
      bool ok; u32 guard = 0;
      do {
        asm volatile(
          "global_load_dwordx4 %0, %6, off sc0 sc1\n\t"
          "global_load_dwordx4 %1, %7, off sc0 sc1\n\t"
          "global_load_dwordx4 %2, %8, off sc0 sc1\n\t"
          "global_load_dwordx4 %3, %9, off sc0 sc1\n\t"
          "global_load_dwordx4 %4, %10, off sc0 sc1\n\t"
          "global_load_dwordx4 %5, %11, off sc0 sc1\n\t"
          "s_waitcnt vmcnt(0)"
          : "=&v"(H0.f), "=&v"(H1.f), "=&v"(H2.f), "=&v"(L0.f), "=&v"(L1.f), "=&v"(L2.f)
          : "v"(a0), "v"(a1_), "v"(a2), "v"(a3), "v"(a4), "v"(a5)
          : "memory");
        int mine = (H0.u[3]==tg) && (H1.u[3]==tg) && (H2.u[3]==tg)
                && (L0.u[3]==tg) && (L1.u[3]==tg) && (L2.u[3]==tg);
        ok = __all(mine) != 0;
      } while (!ok && ++guard < POLL_GUARD);
    }
    // stage payloads to ldsH (3 dwords per unit; pad cols absorb u=5 tails)
    {
      u16* p;
      p = &ldsH[0][rw0][cb0]; *(u32*)p = H0.u[0]; *(u32*)(p+2) = H0.u[1]; *(u32*)(p+4) = H0.u[2];
      p = &ldsH[0][rw1][cb1]; *(u32*)p = H1.u[0]; *(u32*)(p+2) = H1.u[1]; *(u32*)(p+4) = H1.u[2];
      p = &ldsH[0][rw2][cb2]; *(u32*)p = H2.u[0]; *(u32*)(p+2) = H2.u[1]; *(u32*)(p+4) = H2.u[2];
      p = &ldsH[1][rw0][cb0]; *(u32*)p = L0.u[0]; *(u32*)(p+2) = L0.u[1]; *(u32*)(p+4) = L0.u[2];
      p = &ldsH[1][rw1][cb1]; *(u32*)p = L1.u[0]; *(u32*)(p+2) = L1.u[1]; *(u32*)(p+4) = L1.u[2];
      p = &ldsH[1][rw2][cb2]; *(u32*)p = L2.u[0]; *(u32*)(p+2) = L2.u[1]; *(u32*)(p+4) = L2.u[2];
    }
    __syncthreads();
    // G: h-phase MFMAs; rows 0..7 hi plane, 8..15 lo plane (dedup)
    f32x4 c0a = {0.f,0.f,0.f,0.f}, c0b = {0.f,0.f,0.f,0.f};
    f32x4 c1a = {0.f,0.f,0.f,0.f}, c1b = {0.f,0.f,0.f,0.f};
    #pragma unroll
    for (int kt = 0; kt < 8; ++kt){
      short8 ah = *(const short8*)(hrow + goff[kt]);
      c0a = __builtin_amdgcn_mfma_f32_16x16x32_bf16(ah, b2[0][kt], c0a, 0, 0, 0);
      c1a = __builtin_amdgcn_mfma_f32_16x16x32_bf16(ah, b2[1][kt], c1a, 0, 0, 0);
    }
    #pragma unroll
    for (int kt = 8; kt < 16; ++kt){
      short8 ah = *(const short8*)(hrow + goff[kt]);
      c0b = __builtin_amdgcn_mfma_f32_16x16x32_bf16(ah, b2[0][kt], c0b, 0, 0, 0);
      c1b = __builtin_amdgcn_mfma_f32_16x16x32_bf16(ah, b2[1][kt], c1b, 0, 0, 0);
    }
    const f32x4 acc0 = (aX0 + c0a) + c0b;
    const f32x4 acc1 = (aX1 + c1a) + c1b;
    // H: D -> LDS (C/D layout: col=lane&15, row=(lane>>4)*4+reg)
    #pragma unroll
    for (int jj = 0; jj < 4; ++jj){
      ldsD[l4*4 + jj][(2*v + 0)*16 + l15] = acc0[jj];
      ldsD[l4*4 + jj][(2*v + 1)*16 + l15] = acc1[jj];
    }
    __syncthreads();
    const f32x4 pa = *(const f32x4*)&ldsD[er][ehc*4];       // hi rows (+x)
    const f32x4 pb = *(const f32x4*)&ldsD[er + 8][ehc*4];   // lo rows
    const float iv = sigf(pa[0] + pb[0] + tb0);
    const float fv = sigf(pa[1] + pb[1] + tb1);
    const float gv = tanh_f(pa[2] + pb[2] + tb2);
    const float ov = sigf(pa[3] + pb[3] + tb3);
    c_val = fv*c_val + iv*gv;
    const float hval = ov*tanh_f(c_val);
    // pack this cell (hi|lo<<16) in-register
    const u16 hi_ = f2bf(hval);
    const u16 lo_ = f2bf(hval - bf2f(hi_));
    const u32 pcell = (u32)hi_ | ((u32)lo_ << 16);
    if (t == 511) hf[eb*512 + ecol] = hval;
    // per-WAVE shfl-pack publish: lanes<24 gather their unit's 6 cells and store.
    // All lanes execute the shuffles (uniform); only lanes<24 store.
    if (t < 511){
      u32 s0 = __shfl(pcell, pub_srcbase + 0);
      u32 s1 = __shfl(pcell, pub_srcbase + 1);
      u32 s2 = __shfl(pcell, pub_srcbase + 2);
      u32 s3 = __shfl(pcell, pub_srcbase + 3);
      u32 s4 = __shfl(pcell, pub_srcbase + 4);
      u32 s5 = __shfl(pcell, pub_srcbase + 5);
      if (lane < 24){
        u16 v0,v1,v2,v3,v4,v5;
        if (pub_plane){ v0=(u16)(s0>>16); v1=(u16)(s1>>16); v2=(u16)(s2>>16);
                        v3=(u16)(s3>>16); v4=(u16)(s4>>16); v5=(u16)(s5>>16); }
        else          { v0=(u16)s0; v1=(u16)s1; v2=(u16)s2;
                        v3=(u16)s3; v4=(u16)s4; v5=(u16)s5; }
        if (pub_u == 5){ v2 = 0; v3 = 0; v4 = 0; v5 = 0; }   // cols 32..35 don't exist
        F4 D;
        D.u[0] = (u32)v0 | ((u32)v1<<16);
        D.u[1] = (u32)v2 | ((u32)v3<<16);
        D.u[2] = (u32)v4 | ((u32)v5<<16);
        D.u[3] = (u32)(t + 1);
        u32* dst = U + (size_t)(((u32)((t+1)&1))*24576 + pub_off)*4;
        asm volatile("global_store_dwordx4 %0, %1, off sc0 sc1" :: "v"(dst), "v"(D.f) : "memory");
      }
    }
    // drain e-loads (and fire-and-forget unit stores) before conversion
    asm volatile("s_waitcnt vmcnt(0)" ::: "memory");
    // J: convert next-step embedding
    #pragma unroll
    for (int kt = 0; kt < 8; ++kt){
      union { short8 s; u32 u[4]; } pk;
      asm volatile("v_cvt_pk_bf16_f32 %0, %1, %2" : "=v"(pk.u[0]) : "v"(e[2*kt][0]),   "v"(e[2*kt][1]));
      asm volatile("v_cvt_pk_bf16_f32 %0, %1, %2" : "=v"(pk.u[1]) : "v"(e[2*kt][2]),   "v"(e[2*kt][3]));
      asm volatile("v_cvt_pk_bf16_f32 %0, %1, %2" : "=v"(pk.u[2]) : "v"(e[2*kt+1][0]), "v"(e[2*kt+1][1]));
      asm volatile("v_cvt_pk_bf16_f32 %0, %1, %2" : "=v"(pk.u[3]) : "v"(e[2*kt+1][2]), "v"(e[2*kt+1][3]));
      a1n[kt] = (l15 < 8) ? pk.s : z8;
    }
  };

  for (int t = 0; t < 512; t += 2){
    step(t,     a1A, a1B);
    step(t + 1, a1B, a1A);
  }
}

// ---- head: hid = h @ fc1_w^T + fc1_b   (f32)
__global__ void k_head1(const float* __restrict__ hf, const float* __restrict__ w1,
                        const float* __restrict__ b1v, float* __restrict__ hid){
  int b = blockIdx.y;
  int j = blockIdx.x*256 + threadIdx.x;
  if (j >= 500) return;
  float acc = b1v[j];
  const float* hr = hf + b*512;
  const float* wr = w1 + j*512;
  for (int k = 0; k < 512; ++k) acc += hr[k]*wr[k];
  hid[b*500 + j] = acc;
}

// ---- head: logits = hid @ fc2_w^T + fc2_b   (f32 out)
__global__ void k_head2(const float* __restrict__ hid, const float* __restrict__ w2,
                        const float* __restrict__ b2v, float* __restrict__ out){
  int o = blockIdx.x*256 + threadIdx.x;
  if (o >= 640) return;
  int b = o / 5, cls = o % 5;
  float acc = b2v[cls];
  const float* hr = hid + b*500;
  const float* wr = w2 + cls*500;
  for (int j = 0; j < 500; ++j) acc += hr[j]*wr[j];
  out[o] = acc;
}

extern "C" void kernel_launch(void* const* d_in, const int* in_sizes, int n_in,
                              void* d_out, int out_size, void* d_ws, size_t ws_size,
                              hipStream_t stream) {
  const int*   x     = (const int*)d_in[0];
  const float* topic = (const float*)d_in[1];
  const float* h0    = (const float*)d_in[2];
  const float* c0    = (const float*)d_in[3];
  const float* embed = (const float*)d_in[4];
  const float* Wx    = (const float*)d_in[5];
  const float* Wt    = (const float*)d_in[6];
  const float* Wh    = (const float*)d_in[7];
  const float* bias  = (const float*)d_in[8];
  const float* fc1w  = (const float*)d_in[9];
  const float* fc1b  = (const float*)d_in[10];
  const float* fc2w  = (const float*)d_in[11];
  const float* fc2b  = (const float*)d_in[12];

  char* ws = (char*)d_ws;              // 5.0 MB high-water
  u16*   WhT = (u16*)(ws + 0);         // 2048*512*2  = 2097152
  u16*   WxT = (u16*)(ws + 2097152);   // 2048*256*2  = 1048576
  float* tb  = (float*)(ws + 3145728); // 128*2048*4  = 1048576 (dead after k_rnn)
  u32*   U   = (u32*)(ws + 4194304);   // 49152 units * 16B = 786432
  float* hf  = (float*)(ws + 4980736); // 128*512*4   = 262144
  float* hid = (float*)(ws + 3145728); // alias tb (k_head1 runs after k_rnn)

  k_prep<<<dim3(1536), dim3(32, 8), 0, stream>>>(Wh, Wx, WhT, WxT);
  k_topic<<<dim3(8, 128), dim3(256), 0, stream>>>(topic, Wt, bias, tb);
  k_init<<<dim3(192), dim3(256), 0, stream>>>(h0, U);

  k_rnn<<<dim3(256), dim3(256), 0, stream>>>(x, embed, c0, WhT, WxT, tb, U, hf);

  k_head1<<<dim3(2, 128), dim3(256), 0, stream>>>(hf, fc1w, fc1b, hid);
  k_head2<<<dim3(3), dim3(256), 0, stream>>>(hid, fc2w, fc2b, (float*)d_out);
}

// Round 13
// 1920.397 us; speedup vs baseline: 1.0851x; 1.0851x over previous
//
#include <hip/hip_runtime.h>
#include <hip/hip_bf16.h>

typedef unsigned short u16;
typedef unsigned int u32;
typedef __attribute__((ext_vector_type(8))) short short8;
typedef __attribute__((ext_vector_type(4))) float f32x4;

// sizes: V=50000 E=256 H=512 T=50 C=5 B=128 S=512 FC1=500, 4H=2048
// ALL float tensors are f32 on device; x is int32; d_out is f32.
// PROTOCOL LAWS: one tier (sc0 sc1); vmcnt(0) only (fused in-asm); watchdog.
// h transported as self-validating 16B units {6 bf16 + u32 step-tag}.
// R13: R11 base; DELETED vestigial post-publish vmcnt(0) (tags make store-ack
// unnecessary); split MFMA accumulator chains (x: 2->4, G: 4->8).

__device__ __forceinline__ float bf2f(u16 v){ union{u32 u; float f;} x; x.u = ((u32)v)<<16; return x.f; }
__device__ __forceinline__ u16 f2bf(float f){ union{float f; u32 u;} x; x.f = f; u32 r = ((x.u>>16)&1u) + 0x7FFFu; return (u16)((x.u + r)>>16); }
__device__ __forceinline__ float sigf(float x){ return 1.f/(1.f+__expf(-x)); }
__device__ __forceinline__ float tanh_f(float x){ return 2.f/(1.f+__expf(-2.f*x)) - 1.f; }

#define POLL_GUARD (1u<<14)

// unit index (within parity): (((g*2+plane)*8+row)*16+prod)*6+u ; 24576/parity.

// ---- transpose+cast: W_h f32 [512][2048] -> WhT bf16 [2048][512]
//                      W_x f32 [256][2048] -> WxT bf16 [2048][256]
__global__ void k_prep(const float* __restrict__ Wh, const float* __restrict__ Wx,
                       u16* __restrict__ WhT, u16* __restrict__ WxT){
  __shared__ u16 tile[32][33];
  int b = blockIdx.x;
  const float* src; u16* dst; int K, kt, nt;
  if (b < 1024){ src = Wh; dst = WhT; K = 512; kt = b & 15; nt = b >> 4; }
  else { b -= 1024; src = Wx; dst = WxT; K = 256; kt = b & 7; nt = b >> 3; }
  int tx = threadIdx.x, ty = threadIdx.y;
  #pragma unroll
  for (int p = 0; p < 4; ++p){
    int r = p*8 + ty;
    tile[r][tx] = f2bf(src[(kt*32 + r)*2048 + nt*32 + tx]);
  }
  __syncthreads();
  #pragma unroll
  for (int p = 0; p < 4; ++p){
    int r = p*8 + ty;
    dst[(nt*32 + r)*K + kt*32 + tx] = tile[tx][r];
  }
}

// ---- tb[b][col] = bias[col] + sum_t topic[b][t]*W_t[t][col]   (all f32)
__global__ void k_topic(const float* __restrict__ topic, const float* __restrict__ Wt,
                        const float* __restrict__ bias, float* __restrict__ tb){
  int b = blockIdx.y;
  int col = blockIdx.x*256 + threadIdx.x;
  float acc = bias[col];
  #pragma unroll 5
  for (int t = 0; t < 50; ++t)
    acc += topic[b*50 + t] * Wt[t*2048 + col];
  tb[b*2048 + col] = acc;
}

// ---- init units: parity0 = h0 split hi/lo, tag 0; parity1 = tag 0xFFFFFFFF.
__global__ void k_init(const float* __restrict__ h0, u32* __restrict__ U){
  int uid = blockIdx.x*256 + threadIdx.x;
  int parity = (uid >= 24576) ? 1 : 0;
  int rem = uid - parity*24576;
  int g     = rem / 1536;   int r2 = rem - g*1536;
  int plane = r2 / 768;     int pid = r2 - plane*768;
  int row   = pid / 96;     int p3 = pid - row*96;
  int prod  = p3 / 6;       int u  = p3 - prod*6;
  u32 d0=0, d1=0, d2=0, d3;
  if (parity == 0){
    const float* hr = h0 + (g*8 + row)*512 + prod*32 + u*6;
    int nv = 32 - u*6; if (nv > 6) nv = 6;
    u16 vals[6] = {0,0,0,0,0,0};
    for (int j = 0; j < nv; ++j){
      float v = hr[j];
      u16 hi = f2bf(v);
      vals[j] = plane ? f2bf(v - bf2f(hi)) : hi;
    }
    d0 = (u32)vals[0] | ((u32)vals[1]<<16);
    d1 = (u32)vals[2] | ((u32)vals[3]<<16);
    d2 = (u32)vals[4] | ((u32)vals[5]<<16);
    d3 = 0u;                  // tag = 0 (state S_0)
  } else {
    d3 = 0xFFFFFFFFu;         // invalid tag
  }
  u32* dst = U + (size_t)uid*4;
  dst[0]=d0; dst[1]=d1; dst[2]=d2; dst[3]=d3;
}

// ---- persistent LSTM: 256 wgs = 16 batch-groups (8 rows) x 16 col-wgs
__global__ void __launch_bounds__(256, 1)
k_rnn(const int* __restrict__ x, const float* __restrict__ embed, const float* __restrict__ c0,
      const u16* __restrict__ WhT, const u16* __restrict__ WxT, const float* __restrict__ tb,
      u32* __restrict__ U, float* __restrict__ hf)
{
  const int bx = blockIdx.x;
  const int g = bx & 15;      // batch group
  const int w = bx >> 4;      // h-column chunk [w*32, w*32+32)
  const int tid = threadIdx.x;
  const int v = tid >> 6;     // wave 0..3
  const int lane = tid & 63;
  const int l15 = lane & 15, l4 = lane >> 4;
  const int arr = l15 & 7;    // A row within 8
  const int pl  = l15 >> 3;   // 0 = hi plane, 1 = lo plane

  __shared__ __align__(16) u16 ldsH[2][8][704];   // 22KB
  __shared__ __align__(16) float ldsD[16][132];   // 8.4KB
  __shared__ int ldsX[8][512];                    // 16KB
  __shared__ u32 ldsP[8][32];                     // packed hi|lo<<16 per cell, 1KB

  // epilogue cell: thread owns (row er, h-col ehc)
  const int er = tid >> 5, ehc = tid & 31;
  const int eb = g*8 + er;
  const int ecol = w*32 + ehc;
  float c_val = c0[eb*512 + ecol];
  const float tb0 = tb[eb*2048 +    0 + ecol];
  const float tb1 = tb[eb*2048 +  512 + ecol];
  const float tb2 = tb[eb*2048 + 1024 + ecol];
  const float tb3 = tb[eb*2048 + 1536 + ecol];

  // preload B fragments (step-invariant)
  short8 b2[2][16], b1[2][8];
  #pragma unroll
  for (int j = 0; j < 2; ++j){
    const int cl = (2*v + j)*16 + l15;
    const int cg = (cl & 3)*512 + w*32 + (cl >> 2);
    #pragma unroll
    for (int kt = 0; kt < 16; ++kt)
      b2[j][kt] = *(const short8*)(WhT + cg*512 + kt*32 + l4*8);
    #pragma unroll
    for (int kt = 0; kt < 8; ++kt)
      b1[j][kt] = *(const short8*)(WxT + cg*256 + kt*32 + l4*8);
  }

  // stage this group's x block into LDS (8 rows x 512)
  {
    const int4* src = (const int4*)(x + g*4096);
    int4* dst = (int4*)&ldsX[0][0];
    #pragma unroll
    for (int i = 0; i < 4; ++i) dst[tid + 256*i] = src[tid + 256*i];
  }
  __syncthreads();

  // consumer decode: 3 unit slots per thread (pid = tid*3+i), hi plane; lo = +768
  int rw0,rw1,rw2, cb0,cb1,cb2; u32 of0,of1,of2;
  {
    int pid, row, p3, prod, u;
    pid = tid*3 + 0; row = pid/96; p3 = pid - row*96; prod = p3/6; u = p3 - prod*6;
    rw0 = row; cb0 = prod*40 + u*6 + row*8; of0 = (u32)((((g*2+0)*8+row)*16+prod)*6+u);
    pid = tid*3 + 1; row = pid/96; p3 = pid - row*96; prod = p3/6; u = p3 - prod*6;
    rw1 = row; cb1 = prod*40 + u*6 + row*8; of1 = (u32)((((g*2+0)*8+row)*16+prod)*6+u);
    pid = tid*3 + 2; row = pid/96; p3 = pid - row*96; prod = p3/6; u = p3 - prod*6;
    rw2 = row; cb2 = prod*40 + u*6 + row*8; of2 = (u32)((((g*2+0)*8+row)*16+prod)*6+u);
  }
  // producer (packer) decode: threads 0..95
  int pk_plane=0, pk_row=0, pk_ucol=0, pk_nv=0; u32 pk_off=0;
  if (tid < 96){
    pk_plane = tid/48; int rem = tid - pk_plane*48;
    pk_row = rem/6; int u = rem - pk_row*6;
    pk_ucol = u*6;
    pk_nv = 32 - pk_ucol; if (pk_nv > 6) pk_nv = 6;
    pk_off = (u32)((((g*2+pk_plane)*8+pk_row)*16 + w)*6 + u);
  }
  // G-phase step-invariant read offsets
  int goff[16];
  #pragma unroll
  for (int kt = 0; kt < 16; ++kt) goff[kt] = kt*40 + l4*8 + arr*8;
  const u16* hrow = &ldsH[pl][arr][0];

  const short8 z8 = {0,0,0,0,0,0,0,0};
  short8 a1A[8], a1B[8];
  {
    const int idx0 = ldsX[arr][0];
    const float* ep = embed + (u32)idx0*256 + l4*8;
    #pragma unroll
    for (int kt = 0; kt < 8; ++kt){
      float4 f0 = *(const float4*)(ep + kt*32);
      float4 f1 = *(const float4*)(ep + kt*32 + 4);
      union { short8 s; u32 u[4]; } pk;
      asm("v_cvt_pk_bf16_f32 %0, %1, %2" : "=v"(pk.u[0]) : "v"(f0.x), "v"(f0.y));
      asm("v_cvt_pk_bf16_f32 %0, %1, %2" : "=v"(pk.u[1]) : "v"(f0.z), "v"(f0.w));
      asm("v_cvt_pk_bf16_f32 %0, %1, %2" : "=v"(pk.u[2]) : "v"(f1.x), "v"(f1.y));
      asm("v_cvt_pk_bf16_f32 %0, %1, %2" : "=v"(pk.u[3]) : "v"(f1.z), "v"(f1.w));
      a1A[kt] = (l15 < 8) ? pk.s : z8;   // rows 8..15: zero x-contribution
    }
  }

  union F4 { f32x4 f; u32 u[4]; };

  auto step = [&](int t, short8 (&a1c)[8], short8 (&a1n)[8]){
    // P0: issue next-step embedding loads (drained by the poll's in-asm vmcnt(0))
    const int tn = (t < 511) ? t + 1 : 511;
    const int idxn = ldsX[arr][tn];
    const float* ep = embed + (u32)idxn*256 + l4*8;
    f32x4 e[16];
    #pragma unroll
    for (int kt = 0; kt < 8; ++kt){
      asm volatile("global_load_dwordx4 %0, %2, off\n\t"
                   "global_load_dwordx4 %1, %3, off"
                   : "=v"(e[2*kt]), "=v"(e[2*kt+1])
                   : "v"(ep + kt*32), "v"(ep + kt*32 + 4));
    }
    // A: x-phase MFMAs (register-only; 4 independent chains of 4)
    f32x4 aX0a = {0.f,0.f,0.f,0.f}, aX0b = {0.f,0.f,0.f,0.f};
    f32x4 aX1a = {0.f,0.f,0.f,0.f}, aX1b = {0.f,0.f,0.f,0.f};
    #pragma unroll
    for (int kt = 0; kt < 4; ++kt){
      aX0a = __builtin_amdgcn_mfma_f32_16x16x32_bf16(a1c[kt], b1[0][kt], aX0a, 0, 0, 0);
      aX1a = __builtin_amdgcn_mfma_f32_16x16x32_bf16(a1c[kt], b1[1][kt], aX1a, 0, 0, 0);
    }
    #pragma unroll
    for (int kt = 4; kt < 8; ++kt){
      aX0b = __builtin_amdgcn_mfma_f32_16x16x32_bf16(a1c[kt], b1[0][kt], aX0b, 0, 0, 0);
      aX1b = __builtin_amdgcn_mfma_f32_16x16x32_bf16(a1c[kt], b1[1][kt], aX1b, 0, 0, 0);
    }
    const f32x4 aX0 = aX0a + aX0b;
    const f32x4 aX1 = aX1a + aX1b;
    // B: tag-poll — 6 self-validating units per thread (tag==t => payload is S_t)
    F4 H0,H1,H2,L0,L1,L2;
    {
      const u32* b = U + (size_t)((t & 1)*24576)*4;
      const u32 *a0 = b + (size_t)of0*4,      *a1_ = b + (size_t)of1*4,      *a2 = b + (size_t)of2*4;
      const u32 *a3 = b + (size_t)(of0+768)*4,*a4 = b + (size_t)(of1+768)*4, *a5 = b + (size_t)(of2+768)*4;
      const u32 tg = (u32)t;
      bool ok; u32 guard = 0;
      do {
        asm volatile(
          "global_load_dwordx4 %0, %6, off sc0 sc1\n\t"
          "global_load_dwordx4 %1, %7, off sc0 sc1\n\t"
          "global_load_dwordx4 %2, %8, off sc0 sc1\n\t"
          "global_load_dwordx4 %3, %9, off sc0 sc1\n\t"
          "global_load_dwordx4 %4, %10, off sc0 sc1\n\t"
          "global_load_dwordx4 %5, %11, off sc0 sc1\n\t"
          "s_waitcnt vmcnt(0)"
          : "=&v"(H0.f), "=&v"(H1.f), "=&v"(H2.f), "=&v"(L0.f), "=&v"(L1.f), "=&v"(L2.f)
          : "v"(a0), "v"(a1_), "v"(a2), "v"(a3), "v"(a4), "v"(a5)
          : "memory");
        int mine = (H0.u[3]==tg) && (H1.u[3]==tg) && (H2.u[3]==tg)
                && (L0.u[3]==tg) && (L1.u[3]==tg) && (L2.u[3]==tg);
        ok = __all(mine) != 0;
      } while (!ok && ++guard < POLL_GUARD);
    }
    // stage payloads to ldsH (3 dwords per unit; pad cols absorb u=5 tails)
    {
      u16* p;
      p = &ldsH[0][rw0][cb0]; *(u32*)p = H0.u[0]; *(u32*)(p+2) = H0.u[1]; *(u32*)(p+4) = H0.u[2];
      p = &ldsH[0][rw1][cb1]; *(u32*)p = H1.u[0]; *(u32*)(p+2) = H1.u[1]; *(u32*)(p+4) = H1.u[2];
      p = &ldsH[0][rw2][cb2]; *(u32*)p = H2.u[0]; *(u32*)(p+2) = H2.u[1]; *(u32*)(p+4) = H2.u[2];
      p = &ldsH[1][rw0][cb0]; *(u32*)p = L0.u[0]; *(u32*)(p+2) = L0.u[1]; *(u32*)(p+4) = L0.u[2];
      p = &ldsH[1][rw1][cb1]; *(u32*)p = L1.u[0]; *(u32*)(p+2) = L1.u[1]; *(u32*)(p+4) = L1.u[2];
      p = &ldsH[1][rw2][cb2]; *(u32*)p = L2.u[0]; *(u32*)(p+2) = L2.u[1]; *(u32*)(p+4) = L2.u[2];
    }
    __syncthreads();
    // G: h-phase MFMAs; 8 independent chains of 4 (rows 0..7 hi, 8..15 lo)
    f32x4 c0a={0.f,0.f,0.f,0.f}, c0b={0.f,0.f,0.f,0.f}, c0c={0.f,0.f,0.f,0.f}, c0d={0.f,0.f,0.f,0.f};
    f32x4 c1a={0.f,0.f,0.f,0.f}, c1b={0.f,0.f,0.f,0.f}, c1c={0.f,0.f,0.f,0.f}, c1d={0.f,0.f,0.f,0.f};
    #pragma unroll
    for (int kt = 0; kt < 4; ++kt){
      short8 ah = *(const short8*)(hrow + goff[kt]);
      c0a = __builtin_amdgcn_mfma_f32_16x16x32_bf16(ah, b2[0][kt], c0a, 0, 0, 0);
      c1a = __builtin_amdgcn_mfma_f32_16x16x32_bf16(ah, b2[1][kt], c1a, 0, 0, 0);
    }
    #pragma unroll
    for (int kt = 4; kt < 8; ++kt){
      short8 ah = *(const short8*)(hrow + goff[kt]);
      c0b = __builtin_amdgcn_mfma_f32_16x16x32_bf16(ah, b2[0][kt], c0b, 0, 0, 0);
      c1b = __builtin_amdgcn_mfma_f32_16x16x32_bf16(ah, b2[1][kt], c1b, 0, 0, 0);
    }
    #pragma unroll
    for (int kt = 8; kt < 12; ++kt){
      short8 ah = *(const short8*)(hrow + goff[kt]);
      c0c = __builtin_amdgcn_mfma_f32_16x16x32_bf16(ah, b2[0][kt], c0c, 0, 0, 0);
      c1c = __builtin_amdgcn_mfma_f32_16x16x32_bf16(ah, b2[1][kt], c1c, 0, 0, 0);
    }
    #pragma unroll
    for (int kt = 12; kt < 16; ++kt){
      short8 ah = *(const short8*)(hrow + goff[kt]);
      c0d = __builtin_amdgcn_mfma_f32_16x16x32_bf16(ah, b2[0][kt], c0d, 0, 0, 0);
      c1d = __builtin_amdgcn_mfma_f32_16x16x32_bf16(ah, b2[1][kt], c1d, 0, 0, 0);
    }
    const f32x4 acc0 = (aX0 + (c0a + c0b)) + (c0c + c0d);
    const f32x4 acc1 = (aX1 + (c1a + c1b)) + (c1c + c1d);
    // H: D -> LDS (C/D layout: col=lane&15, row=(lane>>4)*4+reg)
    #pragma unroll
    for (int jj = 0; jj < 4; ++jj){
      ldsD[l4*4 + jj][(2*v + 0)*16 + l15] = acc0[jj];
      ldsD[l4*4 + jj][(2*v + 1)*16 + l15] = acc1[jj];
    }
    __syncthreads();
    const f32x4 pa = *(const f32x4*)&ldsD[er][ehc*4];       // hi rows (+x)
    const f32x4 pb = *(const f32x4*)&ldsD[er + 8][ehc*4];   // lo rows
    const float iv = sigf(pa[0] + pb[0] + tb0);
    const float fv = sigf(pa[1] + pb[1] + tb1);
    const float gv = tanh_f(pa[2] + pb[2] + tb2);
    const float ov = sigf(pa[3] + pb[3] + tb3);
    c_val = fv*c_val + iv*gv;
    const float hval = ov*tanh_f(c_val);
    // publish cell to ldsP (hi|lo<<16) for the packers
    {
      const u16 hi = f2bf(hval);
      const u16 lo = f2bf(hval - bf2f(hi));
      ldsP[er][ehc] = (u32)hi | ((u32)lo << 16);
    }
    if (t == 511) hf[eb*512 + ecol] = hval;
    __syncthreads();   // ldsP complete
    // pack + store 96 tagged units (threads 0..95) — FIRE-AND-FORGET:
    // tags carry validity; no store-ack needed (the vestigial vmcnt(0) that
    // followed here cost a full LLC RT per step and protected nothing).
    if (t < 511 && tid < 96){
      u32 x0 = ldsP[pk_row][(pk_ucol+0) & 31];
      u32 x1 = ldsP[pk_row][(pk_ucol+1) & 31];
      u32 x2 = ldsP[pk_row][(pk_ucol+2) & 31];
      u32 x3 = ldsP[pk_row][(pk_ucol+3) & 31];
      u32 x4 = ldsP[pk_row][(pk_ucol+4) & 31];
      u32 x5 = ldsP[pk_row][(pk_ucol+5) & 31];
      if (pk_nv < 6){ x2 = 0; x3 = 0; x4 = 0; x5 = 0; }   // u=5: only 2 valid
      u16 v0,v1,v2,v3,v4,v5;
      if (pk_plane){ v0=(u16)(x0>>16); v1=(u16)(x1>>16); v2=(u16)(x2>>16); v3=(u16)(x3>>16); v4=(u16)(x4>>16); v5=(u16)(x5>>16); }
      else        { v0=(u16)x0; v1=(u16)x1; v2=(u16)x2; v3=(u16)x3; v4=(u16)x4; v5=(u16)x5; }
      F4 D;
      D.u[0] = (u32)v0 | ((u32)v1<<16);
      D.u[1] = (u32)v2 | ((u32)v3<<16);
      D.u[2] = (u32)v4 | ((u32)v5<<16);
      D.u[3] = (u32)(t + 1);
      u32* dst = U + (size_t)(((u32)((t+1)&1))*24576 + pk_off)*4;
      asm volatile("global_store_dwordx4 %0, %1, off sc0 sc1" :: "v"(dst), "v"(D.f) : "memory");
    }
    // J: convert next-step embedding (e[] already retired by B's vmcnt(0))
    #pragma unroll
    for (int kt = 0; kt < 8; ++kt){
      union { short8 s; u32 u[4]; } pk;
      asm volatile("v_cvt_pk_bf16_f32 %0, %1, %2" : "=v"(pk.u[0]) : "v"(e[2*kt][0]),   "v"(e[2*kt][1]));
      asm volatile("v_cvt_pk_bf16_f32 %0, %1, %2" : "=v"(pk.u[1]) : "v"(e[2*kt][2]),   "v"(e[2*kt][3]));
      asm volatile("v_cvt_pk_bf16_f32 %0, %1, %2" : "=v"(pk.u[2]) : "v"(e[2*kt+1][0]), "v"(e[2*kt+1][1]));
      asm volatile("v_cvt_pk_bf16_f32 %0, %1, %2" : "=v"(pk.u[3]) : "v"(e[2*kt+1][2]), "v"(e[2*kt+1][3]));
      a1n[kt] = (l15 < 8) ? pk.s : z8;
    }
  };

  for (int t = 0; t < 512; t += 2){
    step(t,     a1A, a1B);
    step(t + 1, a1B, a1A);
  }
}

// ---- head: hid = h @ fc1_w^T + fc1_b   (f32)
__global__ void k_head1(const float* __restrict__ hf, const float* __restrict__ w1,
                        const float* __restrict__ b1v, float* __restrict__ hid){
  int b = blockIdx.y;
  int j = blockIdx.x*256 + threadIdx.x;
  if (j >= 500) return;
  float acc = b1v[j];
  const float* hr = hf + b*512;
  const float* wr = w1 + j*512;
  for (int k = 0; k < 512; ++k) acc += hr[k]*wr[k];
  hid[b*500 + j] = acc;
}

// ---- head: logits = hid @ fc2_w^T + fc2_b   (f32 out)
__global__ void k_head2(const float* __restrict__ hid, const float* __restrict__ w2,
                        const float* __restrict__ b2v, float* __restrict__ out){
  int o = blockIdx.x*256 + threadIdx.x;
  if (o >= 640) return;
  int b = o / 5, cls = o % 5;
  float acc = b2v[cls];
  const float* hr = hid + b*500;
  const float* wr = w2 + cls*500;
  for (int j = 0; j < 500; ++j) acc += hr[j]*wr[j];
  out[o] = acc;
}

extern "C" void kernel_launch(void* const* d_in, const int* in_sizes, int n_in,
                              void* d_out, int out_size, void* d_ws, size_t ws_size,
                              hipStream_t stream) {
  const int*   x     = (const int*)d_in[0];
  const float* topic = (const float*)d_in[1];
  const float* h0    = (const float*)d_in[2];
  const float* c0    = (const float*)d_in[3];
  const float* embed = (const float*)d_in[4];
  const float* Wx    = (const float*)d_in[5];
  const float* Wt    = (const float*)d_in[6];
  const float* Wh    = (const float*)d_in[7];
  const float* bias  = (const float*)d_in[8];
  const float* fc1w  = (const float*)d_in[9];
  const float* fc1b  = (const float*)d_in[10];
  const float* fc2w  = (const float*)d_in[11];
  const float* fc2b  = (const float*)d_in[12];

  char* ws = (char*)d_ws;              // 5.0 MB high-water
  u16*   WhT = (u16*)(ws + 0);         // 2048*512*2  = 2097152
  u16*   WxT = (u16*)(ws + 2097152);   // 2048*256*2  = 1048576
  float* tb  = (float*)(ws + 3145728); // 128*2048*4  = 1048576 (dead after k_rnn)
  u32*   U   = (u32*)(ws + 4194304);   // 49152 units * 16B = 786432
  float* hf  = (float*)(ws + 4980736); // 128*512*4   = 262144
  float* hid = (float*)(ws + 3145728); // alias tb (k_head1 runs after k_rnn)

  k_prep<<<dim3(1536), dim3(32, 8), 0, stream>>>(Wh, Wx, WhT, WxT);
  k_topic<<<dim3(8, 128), dim3(256), 0, stream>>>(topic, Wt, bias, tb);
  k_init<<<dim3(192), dim3(256), 0, stream>>>(h0, U);

  k_rnn<<<dim3(256), dim3(256), 0, stream>>>(x, embed, c0, WhT, WxT, tb, U, hf);

  k_head1<<<dim3(2, 128), dim3(256), 0, stream>>>(hf, fc1w, fc1b, hid);
  k_head2<<<dim3(3), dim3(256), 0, stream>>>(hid, fc2w, fc2b, (float*)d_out);
}

// Round 14
// 1757.161 us; speedup vs baseline: 1.1859x; 1.0929x over previous
//
#include <hip/hip_runtime.h>
#include <hip/hip_bf16.h>

typedef unsigned short u16;
typedef unsigned int u32;
typedef __attribute__((ext_vector_type(8))) short short8;
typedef __attribute__((ext_vector_type(4))) float f32x4;

// sizes: V=50000 E=256 H=512 T=50 C=5 B=128 S=512 FC1=500, 4H=2048
// ALL float tensors are f32 on device; x is int32; d_out is f32.
// PROTOCOL LAWS: one tier (sc0 sc1); vmcnt(0) only (fused in-asm); watchdog.
// h transported as self-validating 16B units {6 bf16 + u32 step-tag}.
// R14: SINGLE-PLANE bf16 h (no hi/lo split) — halves poll/LLC traffic, which
// R10-R13 insensitivity implicates as the binding resource.

__device__ __forceinline__ float bf2f(u16 v){ union{u32 u; float f;} x; x.u = ((u32)v)<<16; return x.f; }
__device__ __forceinline__ u16 f2bf(float f){ union{float f; u32 u;} x; x.f = f; u32 r = ((x.u>>16)&1u) + 0x7FFFu; return (u16)((x.u + r)>>16); }
__device__ __forceinline__ float sigf(float x){ return 1.f/(1.f+__expf(-x)); }
__device__ __forceinline__ float tanh_f(float x){ return 2.f/(1.f+__expf(-2.f*x)) - 1.f; }

#define POLL_GUARD (1u<<14)

// unit index (within parity): ((g*8+row)*16+prod)*6+u ; 12288 units/parity.

// ---- transpose+cast: W_h f32 [512][2048] -> WhT bf16 [2048][512]
//                      W_x f32 [256][2048] -> WxT bf16 [2048][256]
__global__ void k_prep(const float* __restrict__ Wh, const float* __restrict__ Wx,
                       u16* __restrict__ WhT, u16* __restrict__ WxT){
  __shared__ u16 tile[32][33];
  int b = blockIdx.x;
  const float* src; u16* dst; int K, kt, nt;
  if (b < 1024){ src = Wh; dst = WhT; K = 512; kt = b & 15; nt = b >> 4; }
  else { b -= 1024; src = Wx; dst = WxT; K = 256; kt = b & 7; nt = b >> 3; }
  int tx = threadIdx.x, ty = threadIdx.y;
  #pragma unroll
  for (int p = 0; p < 4; ++p){
    int r = p*8 + ty;
    tile[r][tx] = f2bf(src[(kt*32 + r)*2048 + nt*32 + tx]);
  }
  __syncthreads();
  #pragma unroll
  for (int p = 0; p < 4; ++p){
    int r = p*8 + ty;
    dst[(nt*32 + r)*K + kt*32 + tx] = tile[tx][r];
  }
}

// ---- tb[b][col] = bias[col] + sum_t topic[b][t]*W_t[t][col]   (all f32)
__global__ void k_topic(const float* __restrict__ topic, const float* __restrict__ Wt,
                        const float* __restrict__ bias, float* __restrict__ tb){
  int b = blockIdx.y;
  int col = blockIdx.x*256 + threadIdx.x;
  float acc = bias[col];
  #pragma unroll 5
  for (int t = 0; t < 50; ++t)
    acc += topic[b*50 + t] * Wt[t*2048 + col];
  tb[b*2048 + col] = acc;
}

// ---- init units: parity0 = bf16(h0), tag 0; parity1 = tag 0xFFFFFFFF.
// 96 blocks x 256 threads = 24576 units (2 parities x 12288).
__global__ void k_init(const float* __restrict__ h0, u32* __restrict__ U){
  int uid = blockIdx.x*256 + threadIdx.x;
  int parity = (uid >= 12288) ? 1 : 0;
  int rem = uid - parity*12288;
  int g   = rem / 768;   int r2 = rem - g*768;
  int row = r2 / 96;     int p3 = r2 - row*96;
  int prod = p3 / 6;     int u  = p3 - prod*6;
  u32 d0=0, d1=0, d2=0, d3;
  if (parity == 0){
    const float* hr = h0 + (g*8 + row)*512 + prod*32 + u*6;
    int nv = 32 - u*6; if (nv > 6) nv = 6;
    u16 vals[6] = {0,0,0,0,0,0};
    for (int j = 0; j < nv; ++j) vals[j] = f2bf(hr[j]);
    d0 = (u32)vals[0] | ((u32)vals[1]<<16);
    d1 = (u32)vals[2] | ((u32)vals[3]<<16);
    d2 = (u32)vals[4] | ((u32)vals[5]<<16);
    d3 = 0u;                  // tag = 0 (state S_0)
  } else {
    d3 = 0xFFFFFFFFu;         // invalid tag
  }
  u32* dst = U + (size_t)uid*4;
  dst[0]=d0; dst[1]=d1; dst[2]=d2; dst[3]=d3;
}

// ---- persistent LSTM: 256 wgs = 16 batch-groups (8 rows) x 16 col-wgs
// A rows 8..15 duplicate rows 0..7 (D duplicates ignored; epilogue reads 0..7).
__global__ void __launch_bounds__(256, 1)
k_rnn(const int* __restrict__ x, const float* __restrict__ embed, const float* __restrict__ c0,
      const u16* __restrict__ WhT, const u16* __restrict__ WxT, const float* __restrict__ tb,
      u32* __restrict__ U, float* __restrict__ hf)
{
  const int bx = blockIdx.x;
  const int g = bx & 15;      // batch group
  const int w = bx >> 4;      // h-column chunk [w*32, w*32+32)
  const int tid = threadIdx.x;
  const int v = tid >> 6;     // wave 0..3
  const int lane = tid & 63;
  const int l15 = lane & 15, l4 = lane >> 4;
  const int arr = l15 & 7;    // A row within 8 (rows 8..15 duplicate)

  __shared__ __align__(16) u16 ldsH[8][704];      // 11KB, staggered producer slots
  __shared__ __align__(16) float ldsD[16][132];   // 8.4KB
  __shared__ int ldsX[8][512];                    // 16KB
  __shared__ u16 ldsP[8][32];                     // bf16 cell per (row,col), 512B

  // epilogue cell: thread owns (row er, h-col ehc); er in 0..7
  const int er = tid >> 5, ehc = tid & 31;
  const int eb = g*8 + er;
  const int ecol = w*32 + ehc;
  float c_val = c0[eb*512 + ecol];
  const float tb0 = tb[eb*2048 +    0 + ecol];
  const float tb1 = tb[eb*2048 +  512 + ecol];
  const float tb2 = tb[eb*2048 + 1024 + ecol];
  const float tb3 = tb[eb*2048 + 1536 + ecol];

  // preload B fragments (step-invariant)
  short8 b2[2][16], b1[2][8];
  #pragma unroll
  for (int j = 0; j < 2; ++j){
    const int cl = (2*v + j)*16 + l15;
    const int cg = (cl & 3)*512 + w*32 + (cl >> 2);
    #pragma unroll
    for (int kt = 0; kt < 16; ++kt)
      b2[j][kt] = *(const short8*)(WhT + cg*512 + kt*32 + l4*8);
    #pragma unroll
    for (int kt = 0; kt < 8; ++kt)
      b1[j][kt] = *(const short8*)(WxT + cg*256 + kt*32 + l4*8);
  }

  // stage this group's x block into LDS (8 rows x 512)
  {
    const int4* src = (const int4*)(x + g*4096);
    int4* dst = (int4*)&ldsX[0][0];
    #pragma unroll
    for (int i = 0; i < 4; ++i) dst[tid + 256*i] = src[tid + 256*i];
  }
  __syncthreads();

  // consumer decode: 3 unit slots per thread (pid = tid*3+i)
  int rw0,rw1,rw2, cb0,cb1,cb2; u32 of0,of1,of2;
  {
    int pid, row, p3, prod, u;
    pid = tid*3 + 0; row = pid/96; p3 = pid - row*96; prod = p3/6; u = p3 - prod*6;
    rw0 = row; cb0 = prod*40 + u*6 + row*8; of0 = (u32)(((g*8+row)*16+prod)*6+u);
    pid = tid*3 + 1; row = pid/96; p3 = pid - row*96; prod = p3/6; u = p3 - prod*6;
    rw1 = row; cb1 = prod*40 + u*6 + row*8; of1 = (u32)(((g*8+row)*16+prod)*6+u);
    pid = tid*3 + 2; row = pid/96; p3 = pid - row*96; prod = p3/6; u = p3 - prod*6;
    rw2 = row; cb2 = prod*40 + u*6 + row*8; of2 = (u32)(((g*8+row)*16+prod)*6+u);
  }
  // producer (packer) decode: threads 0..47 publish 48 units
  int pk_row=0, pk_ucol=0, pk_nv=0; u32 pk_off=0;
  if (tid < 48){
    pk_row = tid/6; int u = tid - pk_row*6;
    pk_ucol = u*6;
    pk_nv = 32 - pk_ucol; if (pk_nv > 6) pk_nv = 6;
    pk_off = (u32)(((g*8+pk_row)*16 + w)*6 + u);
  }
  // G-phase step-invariant read offsets
  int goff[16];
  #pragma unroll
  for (int kt = 0; kt < 16; ++kt) goff[kt] = kt*40 + l4*8 + arr*8;
  const u16* hrow = &ldsH[arr][0];

  short8 a1A[8], a1B[8];
  {
    const int idx0 = ldsX[arr][0];
    const float* ep = embed + (u32)idx0*256 + l4*8;
    #pragma unroll
    for (int kt = 0; kt < 8; ++kt){
      float4 f0 = *(const float4*)(ep + kt*32);
      float4 f1 = *(const float4*)(ep + kt*32 + 4);
      union { short8 s; u32 u[4]; } pk;
      asm("v_cvt_pk_bf16_f32 %0, %1, %2" : "=v"(pk.u[0]) : "v"(f0.x), "v"(f0.y));
      asm("v_cvt_pk_bf16_f32 %0, %1, %2" : "=v"(pk.u[1]) : "v"(f0.z), "v"(f0.w));
      asm("v_cvt_pk_bf16_f32 %0, %1, %2" : "=v"(pk.u[2]) : "v"(f1.x), "v"(f1.y));
      asm("v_cvt_pk_bf16_f32 %0, %1, %2" : "=v"(pk.u[3]) : "v"(f1.z), "v"(f1.w));
      a1A[kt] = pk.s;   // rows 8..15 duplicate rows 0..7 (same arr)
    }
  }

  union F4 { f32x4 f; u32 u[4]; };

  auto step = [&](int t, short8 (&a1c)[8], short8 (&a1n)[8]){
    // P0: issue next-step embedding loads (drained by the poll's in-asm vmcnt(0))
    const int tn = (t < 511) ? t + 1 : 511;
    const int idxn = ldsX[arr][tn];
    const float* ep = embed + (u32)idxn*256 + l4*8;
    f32x4 e[16];
    #pragma unroll
    for (int kt = 0; kt < 8; ++kt){
      asm volatile("global_load_dwordx4 %0, %2, off\n\t"
                   "global_load_dwordx4 %1, %3, off"
                   : "=v"(e[2*kt]), "=v"(e[2*kt+1])
                   : "v"(ep + kt*32), "v"(ep + kt*32 + 4));
    }
    // A: x-phase MFMAs (register-only; 4 independent chains of 4)
    f32x4 aX0a = {0.f,0.f,0.f,0.f}, aX0b = {0.f,0.f,0.f,0.f};
    f32x4 aX1a = {0.f,0.f,0.f,0.f}, aX1b = {0.f,0.f,0.f,0.f};
    #pragma unroll
    for (int kt = 0; kt < 4; ++kt){
      aX0a = __builtin_amdgcn_mfma_f32_16x16x32_bf16(a1c[kt], b1[0][kt], aX0a, 0, 0, 0);
      aX1a = __builtin_amdgcn_mfma_f32_16x16x32_bf16(a1c[kt], b1[1][kt], aX1a, 0, 0, 0);
    }
    #pragma unroll
    for (int kt = 4; kt < 8; ++kt){
      aX0b = __builtin_amdgcn_mfma_f32_16x16x32_bf16(a1c[kt], b1[0][kt], aX0b, 0, 0, 0);
      aX1b = __builtin_amdgcn_mfma_f32_16x16x32_bf16(a1c[kt], b1[1][kt], aX1b, 0, 0, 0);
    }
    const f32x4 aX0 = aX0a + aX0b;
    const f32x4 aX1 = aX1a + aX1b;
    // B: tag-poll — 3 self-validating units per thread (tag==t => payload is S_t)
    F4 H0,H1,H2;
    {
      const u32* b = U + (size_t)((t & 1)*12288)*4;
      const u32 *a0 = b + (size_t)of0*4, *a1_ = b + (size_t)of1*4, *a2 = b + (size_t)of2*4;
      const u32 tg = (u32)t;
      bool ok; u32 guard = 0;
      do {
        asm volatile(
          "global_load_dwordx4 %0, %3, off sc0 sc1\n\t"
          "global_load_dwordx4 %1, %4, off sc0 sc1\n\t"
          "global_load_dwordx4 %2, %5, off sc0 sc1\n\t"
          "s_waitcnt vmcnt(0)"
          : "=&v"(H0.f), "=&v"(H1.f), "=&v"(H2.f)
          : "v"(a0), "v"(a1_), "v"(a2)
          : "memory");
        int mine = (H0.u[3]==tg) && (H1.u[3]==tg) && (H2.u[3]==tg);
        ok = __all(mine) != 0;
      } while (!ok && ++guard < POLL_GUARD);
    }
    // stage payloads to ldsH (3 dwords per unit; pad cols absorb u=5 tails)
    {
      u16* p;
      p = &ldsH[rw0][cb0]; *(u32*)p = H0.u[0]; *(u32*)(p+2) = H0.u[1]; *(u32*)(p+4) = H0.u[2];
      p = &ldsH[rw1][cb1]; *(u32*)p = H1.u[0]; *(u32*)(p+2) = H1.u[1]; *(u32*)(p+4) = H1.u[2];
      p = &ldsH[rw2][cb2]; *(u32*)p = H2.u[0]; *(u32*)(p+2) = H2.u[1]; *(u32*)(p+4) = H2.u[2];
    }
    __syncthreads();
    // G: h-phase MFMAs; 4 independent chains of 4 per N-tile
    f32x4 c0a={0.f,0.f,0.f,0.f}, c0b={0.f,0.f,0.f,0.f}, c0c={0.f,0.f,0.f,0.f}, c0d={0.f,0.f,0.f,0.f};
    f32x4 c1a={0.f,0.f,0.f,0.f}, c1b={0.f,0.f,0.f,0.f}, c1c={0.f,0.f,0.f,0.f}, c1d={0.f,0.f,0.f,0.f};
    #pragma unroll
    for (int kt = 0; kt < 4; ++kt){
      short8 ah = *(const short8*)(hrow + goff[kt]);
      c0a = __builtin_amdgcn_mfma_f32_16x16x32_bf16(ah, b2[0][kt], c0a, 0, 0, 0);
      c1a = __builtin_amdgcn_mfma_f32_16x16x32_bf16(ah, b2[1][kt], c1a, 0, 0, 0);
    }
    #pragma unroll
    for (int kt = 4; kt < 8; ++kt){
      short8 ah = *(const short8*)(hrow + goff[kt]);
      c0b = __builtin_amdgcn_mfma_f32_16x16x32_bf16(ah, b2[0][kt], c0b, 0, 0, 0);
      c1b = __builtin_amdgcn_mfma_f32_16x16x32_bf16(ah, b2[1][kt], c1b, 0, 0, 0);
    }
    #pragma unroll
    for (int kt = 8; kt < 12; ++kt){
      short8 ah = *(const short8*)(hrow + goff[kt]);
      c0c = __builtin_amdgcn_mfma_f32_16x16x32_bf16(ah, b2[0][kt], c0c, 0, 0, 0);
      c1c = __builtin_amdgcn_mfma_f32_16x16x32_bf16(ah, b2[1][kt], c1c, 0, 0, 0);
    }
    #pragma unroll
    for (int kt = 12; kt < 16; ++kt){
      short8 ah = *(const short8*)(hrow + goff[kt]);
      c0d = __builtin_amdgcn_mfma_f32_16x16x32_bf16(ah, b2[0][kt], c0d, 0, 0, 0);
      c1d = __builtin_amdgcn_mfma_f32_16x16x32_bf16(ah, b2[1][kt], c1d, 0, 0, 0);
    }
    const f32x4 acc0 = (aX0 + (c0a + c0b)) + (c0c + c0d);
    const f32x4 acc1 = (aX1 + (c1a + c1b)) + (c1c + c1d);
    // H: D -> LDS (C/D layout: col=lane&15, row=(lane>>4)*4+reg)
    #pragma unroll
    for (int jj = 0; jj < 4; ++jj){
      ldsD[l4*4 + jj][(2*v + 0)*16 + l15] = acc0[jj];
      ldsD[l4*4 + jj][(2*v + 1)*16 + l15] = acc1[jj];
    }
    __syncthreads();
    const f32x4 pa = *(const f32x4*)&ldsD[er][ehc*4];   // rows 0..7 only
    const float iv = sigf(pa[0] + tb0);
    const float fv = sigf(pa[1] + tb1);
    const float gv = tanh_f(pa[2] + tb2);
    const float ov = sigf(pa[3] + tb3);
    c_val = fv*c_val + iv*gv;
    const float hval = ov*tanh_f(c_val);
    // publish cell (single bf16) to ldsP for the packers
    ldsP[er][ehc] = f2bf(hval);
    if (t == 511) hf[eb*512 + ecol] = hval;
    __syncthreads();   // ldsP complete
    // pack + store 48 tagged units (threads 0..47) — fire-and-forget
    if (t < 511 && tid < 48){
      u16 v0 = ldsP[pk_row][(pk_ucol+0) & 31];
      u16 v1 = ldsP[pk_row][(pk_ucol+1) & 31];
      u16 v2 = ldsP[pk_row][(pk_ucol+2) & 31];
      u16 v3 = ldsP[pk_row][(pk_ucol+3) & 31];
      u16 v4 = ldsP[pk_row][(pk_ucol+4) & 31];
      u16 v5 = ldsP[pk_row][(pk_ucol+5) & 31];
      if (pk_nv < 6){ v2 = 0; v3 = 0; v4 = 0; v5 = 0; }   // u=5: only 2 valid
      F4 D;
      D.u[0] = (u32)v0 | ((u32)v1<<16);
      D.u[1] = (u32)v2 | ((u32)v3<<16);
      D.u[2] = (u32)v4 | ((u32)v5<<16);
      D.u[3] = (u32)(t + 1);
      u32* dst = U + (size_t)(((u32)((t+1)&1))*12288 + pk_off)*4;
      asm volatile("global_store_dwordx4 %0, %1, off sc0 sc1" :: "v"(dst), "v"(D.f) : "memory");
    }
    // J: convert next-step embedding (e[] already retired by B's vmcnt(0))
    #pragma unroll
    for (int kt = 0; kt < 8; ++kt){
      union { short8 s; u32 u[4]; } pk;
      asm volatile("v_cvt_pk_bf16_f32 %0, %1, %2" : "=v"(pk.u[0]) : "v"(e[2*kt][0]),   "v"(e[2*kt][1]));
      asm volatile("v_cvt_pk_bf16_f32 %0, %1, %2" : "=v"(pk.u[1]) : "v"(e[2*kt][2]),   "v"(e[2*kt][3]));
      asm volatile("v_cvt_pk_bf16_f32 %0, %1, %2" : "=v"(pk.u[2]) : "v"(e[2*kt+1][0]), "v"(e[2*kt+1][1]));
      asm volatile("v_cvt_pk_bf16_f32 %0, %1, %2" : "=v"(pk.u[3]) : "v"(e[2*kt+1][2]), "v"(e[2*kt+1][3]));
      a1n[kt] = pk.s;
    }
  };

  for (int t = 0; t < 512; t += 2){
    step(t,     a1A, a1B);
    step(t + 1, a1B, a1A);
  }
}

// ---- head: hid = h @ fc1_w^T + fc1_b   (f32)
__global__ void k_head1(const float* __restrict__ hf, const float* __restrict__ w1,
                        const float* __restrict__ b1v, float* __restrict__ hid){
  int b = blockIdx.y;
  int j = blockIdx.x*256 + threadIdx.x;
  if (j >= 500) return;
  float acc = b1v[j];
  const float* hr = hf + b*512;
  const float* wr = w1 + j*512;
  for (int k = 0; k < 512; ++k) acc += hr[k]*wr[k];
  hid[b*500 + j] = acc;
}

// ---- head: logits = hid @ fc2_w^T + fc2_b   (f32 out)
__global__ void k_head2(const float* __restrict__ hid, const float* __restrict__ w2,
                        const float* __restrict__ b2v, float* __restrict__ out){
  int o = blockIdx.x*256 + threadIdx.x;
  if (o >= 640) return;
  int b = o / 5, cls = o % 5;
  float acc = b2v[cls];
  const float* hr = hid + b*500;
  const float* wr = w2 + cls*500;
  for (int j = 0; j < 500; ++j) acc += hr[j]*wr[j];
  out[o] = acc;
}

extern "C" void kernel_launch(void* const* d_in, const int* in_sizes, int n_in,
                              void* d_out, int out_size, void* d_ws, size_t ws_size,
                              hipStream_t stream) {
  const int*   x     = (const int*)d_in[0];
  const float* topic = (const float*)d_in[1];
  const float* h0    = (const float*)d_in[2];
  const float* c0    = (const float*)d_in[3];
  const float* embed = (const float*)d_in[4];
  const float* Wx    = (const float*)d_in[5];
  const float* Wt    = (const float*)d_in[6];
  const float* Wh    = (const float*)d_in[7];
  const float* bias  = (const float*)d_in[8];
  const float* fc1w  = (const float*)d_in[9];
  const float* fc1b  = (const float*)d_in[10];
  const float* fc2w  = (const float*)d_in[11];
  const float* fc2b  = (const float*)d_in[12];

  char* ws = (char*)d_ws;              // 5.0 MB high-water
  u16*   WhT = (u16*)(ws + 0);         // 2048*512*2  = 2097152
  u16*   WxT = (u16*)(ws + 2097152);   // 2048*256*2  = 1048576
  float* tb  = (float*)(ws + 3145728); // 128*2048*4  = 1048576 (dead after k_rnn)
  u32*   U   = (u32*)(ws + 4194304);   // 24576 units * 16B = 393216
  float* hf  = (float*)(ws + 4980736); // 128*512*4   = 262144
  float* hid = (float*)(ws + 3145728); // alias tb (k_head1 runs after k_rnn)

  k_prep<<<dim3(1536), dim3(32, 8), 0, stream>>>(Wh, Wx, WhT, WxT);
  k_topic<<<dim3(8, 128), dim3(256), 0, stream>>>(topic, Wt, bias, tb);
  k_init<<<dim3(96), dim3(256), 0, stream>>>(h0, U);

  k_rnn<<<dim3(256), dim3(256), 0, stream>>>(x, embed, c0, WhT, WxT, tb, U, hf);

  k_head1<<<dim3(2, 128), dim3(256), 0, stream>>>(hf, fc1w, fc1b, hid);
  k_head2<<<dim3(3), dim3(256), 0, stream>>>(hid, fc2w, fc2b, (float*)d_out);
}